// Round 8
// baseline (1694.012 us; speedup 1.0000x reference)
//
#include <hip/hip_runtime.h>
#include <hip/hip_fp16.h>
#include <stdint.h>

// ---------------------------------------------------------------------------
// SeqAE: enc LSTM (3->200, T=800, B=256) -> maxpool(T) -> dec LSTM (200->3)
// R8: MFMA rewrite. Batch = M dim of mfma_f32_16x16x32_f16. 16 WGs (one per
// 16-batch tile), 256 thr (4 waves, 1/SIMD -> 512-reg budget). Rows permuted
// row'=4u+g so D (col=batch, row=(lane>>4)*4+reg) puts unit u's 4 gates in
// one lane's 4 C regs -> lane-local c/h/maxpool. K=224: h(0..199) + x(200..
// 202) + 1.0*bias(203) -> Wih*x + bias fused into the same MFMAs. Weights =
// A-fragments, 364 dw/thread pinned to AGPRs ("+a") -- MFMA reads A from
// AGPR natively, so residency is finally free (R6/R7's accvgpr-read tax was
// the dot2 design's doom). 91 MFMA + 7 ds_read_b128 + ~260 VALU per
// wave-step, 1 barrier/step, h double-buffered.
// ---------------------------------------------------------------------------

typedef _Float16 f16x8 __attribute__((ext_vector_type(8)));
typedef float f32x4 __attribute__((ext_vector_type(4)));

#define MT_TILES 52
#define KT_TILES 7
#define TPW 13
#define HSTR 116   // dwords per batch row in hbuf (464 B)

__device__ __forceinline__ float hsig(float z) {
  return fminf(fmaxf(__builtin_fmaf(0.2f, z, 0.5f), 0.f), 1.f);
}
__device__ __forceinline__ float tanh_fast(float v) {
  float e = __builtin_amdgcn_exp2f(v * 2.885390081777927f);
  return 1.f - 2.f * __builtin_amdgcn_rcpf(e + 1.f);
}

// ---- prep: pack A-operand fragments (f16 pairs) ----
// layout: wpkA[((mta*7 + kt)*64 + lane)*4 + v]; A[row'][k], row' = tile row,
// lane&15 = row'_loc, k = kt*32 + (lane>>4)*8 + 2v + {0,1}
__global__ void prep_kernel(const float* __restrict__ whh,
                            const float* __restrict__ wih,
                            const float* __restrict__ bih,
                            const float* __restrict__ bhh,
                            uint32_t* __restrict__ wpkA) {
  int idx = blockIdx.x * 256 + threadIdx.x;
  if (idx >= MT_TILES * KT_TILES * 256) return;
  int v = idx & 3;
  int l = (idx >> 2) & 63;
  int mk = idx >> 8;
  int kt = mk % KT_TILES, mta = mk / KT_TILES;
  int rl = l & 15;                    // row within tile: 4*u_loc + g
  int u = mta * 4 + (rl >> 2);        // global unit
  int g = rl & 3;                     // gate (i,f,g,o)
  int kb = kt * 32 + (l >> 4) * 8 + 2 * v;
  float e0 = 0.f, e1 = 0.f;
  if (u < 200) {
    int orig = u + 200 * g;           // original gate row
    int k0 = kb, k1 = kb + 1;
    e0 = (k0 < 200) ? whh[orig * 200 + k0]
       : (k0 < 203) ? wih[orig * 3 + (k0 - 200)]
       : (k0 == 203) ? (bih[orig] + bhh[orig]) : 0.f;
    e1 = (k1 < 200) ? whh[orig * 200 + k1]
       : (k1 < 203) ? wih[orig * 3 + (k1 - 200)]
       : (k1 == 203) ? (bih[orig] + bhh[orig]) : 0.f;
  }
  __half2 h = __floats2half2_rn(e0, e1);
  wpkA[idx] = __builtin_bit_cast(uint32_t, h);
}

// ---- encoder: grid 16 (batch tiles), 256 threads (4 waves, 1/SIMD) ----
__global__ __launch_bounds__(256, 1)
void enc_kernel(const float* __restrict__ x,       // (256,3,800)
                const uint32_t* __restrict__ wpkA, // packed A frags
                const float* __restrict__ dwih,    // (12,200)
                const float* __restrict__ dbih,    // (12)
                const float* __restrict__ dbhh,    // (12)
                float* __restrict__ pre12g)        // (256,12) ws
{
  const int bt = blockIdx.x;
  const int t = threadIdx.x;
  const int lane = t & 63;
  const int w = t >> 6;          // wave 0..3
  const int col = lane & 15;     // batch within tile (B-col / D-col)
  const int kq = lane >> 4;      // 0..3: unit-in-tile for D; k-chunk for B

  __shared__ uint32_t hbuf[2][16 * HSTR];   // B operand: [batch][k] f16
  __shared__ float pooled[16][200];

  for (int i = t; i < 2 * 16 * HSTR; i += 256) ((uint32_t*)hbuf)[i] = 0;

  // ---- load weights: 13 M-tiles x 7 K-tiles, A-fragment per lane ----
  f16x8 wf[TPW][KT_TILES];
#pragma unroll
  for (int mt = 0; mt < TPW; ++mt)
#pragma unroll
    for (int kt = 0; kt < KT_TILES; ++kt) {
      int mta = w * TPW + mt;
      uint4 uv = ((const uint4*)wpkA)[(mta * KT_TILES + kt) * 64 + lane];
      wf[mt][kt] = __builtin_bit_cast(f16x8, uv);
    }
#pragma unroll
  for (int mt = 0; mt < TPW; ++mt)
#pragma unroll
    for (int kt = 0; kt < KT_TILES; ++kt)
      asm volatile("" : "+a"(wf[mt][kt]));   // pin resident (AGPR = free for MFMA A)

  const float* xb = x + (size_t)(bt * 16 + col) * 2400;
  __syncthreads();
  if (w == 0 && lane < 16) {                 // x(0), 1.0 into buf0 k=200..203
    __half2 p01 = __floats2half2_rn(xb[0], xb[800]);
    __half2 p23 = __floats2half2_rn(xb[1600], 1.0f);
    hbuf[0][col * HSTR + 100] = __builtin_bit_cast(uint32_t, p01);
    hbuf[0][col * HSTR + 101] = __builtin_bit_cast(uint32_t, p23);
  }
  __syncthreads();

  float cst[TPW], mx[TPW];
#pragma unroll
  for (int mt = 0; mt < TPW; ++mt) { cst[mt] = 0.f; mx[mt] = -INFINITY; }

  const int rdoff = col * HSTR + kq * 4;     // dwords; + kt*16

#define ENC_STEP(SRC, DST, TT)                                               \
  {                                                                          \
    float x0 = 0.f, x1 = 0.f, x2 = 0.f;                                      \
    const bool dox = (w == 0) && (lane < 16) && ((TT) < 799);                \
    if (dox) { x0 = xb[(TT) + 1]; x1 = xb[800 + (TT) + 1];                   \
               x2 = xb[1600 + (TT) + 1]; }                                   \
    f16x8 bf[KT_TILES];                                                      \
    _Pragma("unroll")                                                        \
    for (int kt = 0; kt < KT_TILES; ++kt)                                    \
      bf[kt] = __builtin_bit_cast(f16x8,                                     \
                 *(const uint4*)&hbuf[SRC][rdoff + kt * 16]);                \
    _Pragma("unroll")                                                        \
    for (int mt = 0; mt < TPW; ++mt) {                                       \
      f32x4 C = {0.f, 0.f, 0.f, 0.f};                                        \
      _Pragma("unroll")                                                      \
      for (int kt = 0; kt < KT_TILES; ++kt)                                  \
        C = __builtin_amdgcn_mfma_f32_16x16x32_f16(wf[mt][kt], bf[kt], C,    \
                                                   0, 0, 0);                 \
      float i_ = hsig(C[0]), f_ = hsig(C[1]), o_ = hsig(C[3]);               \
      float g_ = tanh_fast(C[2]);                                            \
      cst[mt] = __builtin_fmaf(f_, cst[mt], i_ * g_);                        \
      float h_ = o_ * tanh_fast(cst[mt]);                                    \
      mx[mt] = fmaxf(mx[mt], h_);                                            \
      int u = (w * TPW + mt) * 4 + kq;                                       \
      if (u < 200)                                                           \
        ((__half*)hbuf[DST])[col * 232 + u] = __float2half(h_);              \
    }                                                                        \
    if (dox) {                                                               \
      __half2 p01 = __floats2half2_rn(x0, x1);                               \
      __half2 p23 = __floats2half2_rn(x2, 1.0f);                             \
      hbuf[DST][col * HSTR + 100] = __builtin_bit_cast(uint32_t, p01);       \
      hbuf[DST][col * HSTR + 101] = __builtin_bit_cast(uint32_t, p23);       \
    }                                                                        \
    __syncthreads();                                                         \
  }

  for (int sp = 0; sp < 400; ++sp) {
    ENC_STEP(0, 1, 2 * sp)
    ENC_STEP(1, 0, 2 * sp + 1)
  }
#undef ENC_STEP

  // ---- maxpool -> pooled LDS -> pre12 ----
#pragma unroll
  for (int mt = 0; mt < TPW; ++mt) {
    int u = (w * TPW + mt) * 4 + kq;
    if (u < 200) pooled[col][u] = mx[mt];
  }
  __syncthreads();
  if (t < 192) {
    int b = t / 12, j = t % 12;
    float s = dbih[j] + dbhh[j];
    const float* wr = dwih + j * 200;
#pragma unroll 8
    for (int u2 = 0; u2 < 200; ++u2) s = __builtin_fmaf(pooled[b][u2], wr[u2], s);
    pre12g[(bt * 16 + b) * 12 + j] = s;
  }
}

// ---- decoder: 4 WGs x 64 threads, thread = batch. Fixed-point early exit.
__global__ __launch_bounds__(64, 1)
void dec_kernel(const float* __restrict__ pre12,
                const float* __restrict__ dwhh,   // (12,3)
                float* __restrict__ out)          // (256,3,800)
{
  const int lane = threadIdx.x;
  const int b = blockIdx.x * 64 + lane;

  float pre[12];
#pragma unroll
  for (int j = 0; j < 12; ++j) pre[j] = pre12[b * 12 + j];
  float W[36];
#pragma unroll
  for (int j = 0; j < 36; ++j) W[j] = dwhh[j];

  float h0 = 0, h1 = 0, h2 = 0, c0 = 0, c1 = 0, c2 = 0;
  int tc = 800;
  float* ob = out + (size_t)b * 2400;

  for (int step = 0; step < 800; ++step) {
    float g[12];
#pragma unroll
    for (int j = 0; j < 12; ++j) {
      float v = pre[j];
      v = __builtin_fmaf(W[j * 3 + 0], h0, v);
      v = __builtin_fmaf(W[j * 3 + 1], h1, v);
      v = __builtin_fmaf(W[j * 3 + 2], h2, v);
      g[j] = v;
    }
    float nc0 = hsig(g[3]) * c0 + hsig(g[0]) * tanh_fast(g[6]);
    float nc1 = hsig(g[4]) * c1 + hsig(g[1]) * tanh_fast(g[7]);
    float nc2 = hsig(g[5]) * c2 + hsig(g[2]) * tanh_fast(g[8]);
    float nh0 = hsig(g[9])  * tanh_fast(nc0);
    float nh1 = hsig(g[10]) * tanh_fast(nc1);
    float nh2 = hsig(g[11]) * tanh_fast(nc2);
    bool same = (nh0 == h0) && (nh1 == h1) && (nh2 == h2) &&
                (nc0 == c0) && (nc1 == c1) && (nc2 == c2);
    ob[step] = nh0; ob[800 + step] = nh1; ob[1600 + step] = nh2;
    h0 = nh0; h1 = nh1; h2 = nh2; c0 = nc0; c1 = nc1; c2 = nc2;
    if (same) { tc = step + 1; break; }   // exact fixed point
  }

  __shared__ int s_tc[64];
  __shared__ float s_h[64][3];
  s_tc[lane] = tc;
  s_h[lane][0] = h0; s_h[lane][1] = h1; s_h[lane][2] = h2;
  __syncthreads();
  for (int i = 0; i < 64; ++i) {
    const int start = s_tc[i];
    if (start >= 800) continue;
    float v0 = s_h[i][0], v1 = s_h[i][1], v2 = s_h[i][2];
    float* op = out + (size_t)(blockIdx.x * 64 + i) * 2400;
    for (int tt = start + lane; tt < 800; tt += 64) {
      op[tt] = v0; op[800 + tt] = v1; op[1600 + tt] = v2;
    }
  }
}

extern "C" void kernel_launch(void* const* d_in, const int* in_sizes, int n_in,
                              void* d_out, int out_size, void* d_ws, size_t ws_size,
                              hipStream_t stream)
{
  const float* x    = (const float*)d_in[0];
  const float* wih  = (const float*)d_in[1];
  const float* whh  = (const float*)d_in[2];
  const float* bih  = (const float*)d_in[3];
  const float* bhh  = (const float*)d_in[4];
  const float* dwih = (const float*)d_in[5];
  const float* dwhh = (const float*)d_in[6];
  const float* dbih = (const float*)d_in[7];
  const float* dbhh = (const float*)d_in[8];
  float* out = (float*)d_out;

  uint32_t* wpkA = (uint32_t*)d_ws;                     // 372736 B
  float* pre12g  = (float*)((char*)d_ws + 372736);      // 12288 B

  hipLaunchKernelGGL(prep_kernel, dim3(364), dim3(256), 0, stream,
                     whh, wih, bih, bhh, wpkA);
  hipLaunchKernelGGL(enc_kernel, dim3(16), dim3(256), 0, stream,
                     x, wpkA, dwih, dbih, dbhh, pre12g);
  hipLaunchKernelGGL(dec_kernel, dim3(4), dim3(64), 0, stream,
                     pre12g, dwhh, out);
}